// Round 2
// baseline (1128.919 us; speedup 1.0000x reference)
//
#include <hip/hip_runtime.h>
#include <math.h>

#define D_MODEL 1024
#define D_INT   64
#define KW      32
#define L_SEQ   4096
#define SUBHEADS 5
#define HEADS   14
#define M_ROWS  8192
#define N_CAT   896

typedef unsigned short us;
typedef __attribute__((ext_vector_type(8))) short bf16x8_t;
typedef __attribute__((ext_vector_type(4))) float f32x4_t;

__device__ __forceinline__ float b2f(us x) {
    unsigned int u = ((unsigned int)x) << 16;
    float f; __builtin_memcpy(&f, &u, 4); return f;
}
__device__ __forceinline__ us f2b(float f) {
    unsigned int u; __builtin_memcpy(&u, &f, 4);
    u += 0x7fffu + ((u >> 16) & 1u);
    return (us)(u >> 16);
}
__device__ __forceinline__ void load16(void* lds, const void* g) {
    __builtin_amdgcn_global_load_lds(
        (const __attribute__((address_space(1))) unsigned int*)g,
        (__attribute__((address_space(3))) unsigned int*)lds, 16, 0, 0);
}

// ---------------------------------------------------------------------------
// fp32 -> bf16 elementwise cast (float4 in, 4x bf16 out)
// ---------------------------------------------------------------------------
__global__ __launch_bounds__(256)
void cast_bf16(const float4* __restrict__ s, us* __restrict__ d, int n4)
{
    int i = blockIdx.x * 256 + threadIdx.x;
    if (i >= n4) return;
    float4 v = s[i];
    ushort4 o;
    o.x = f2b(v.x); o.y = f2b(v.y); o.z = f2b(v.z); o.w = f2b(v.w);
    ((ushort4*)d)[i] = o;
}

// ---------------------------------------------------------------------------
// transpose + cast: dst[b][n][k] = src[b][k][n]  (bf16 out, k-contiguous)
// ---------------------------------------------------------------------------
__global__ __launch_bounds__(256)
void tcast(const float* __restrict__ s, us* __restrict__ d, int K, int N, int total)
{
    for (int idx = blockIdx.x * 256 + threadIdx.x; idx < total; idx += gridDim.x * 256) {
        int k = idx % K;
        int t = idx / K;
        int n = t % N;
        int b = t / N;
        d[idx] = f2b(s[((size_t)b * K + k) * N + n]);
    }
}

// ---------------------------------------------------------------------------
// bf16 MFMA GEMM: C[b] = A * Bt[b]^T + bias[b]
// A:  [M][K] bf16 row-major (k contiguous), shared across batch
// Bt: [b][N][K] bf16 (k contiguous)
// 64x64 tile, BK=64, 4 waves; wave w computes rows [w*16,w*16+16) x all 64 cols
// via 4x mfma_f32_16x16x32_bf16. XOR-swizzled LDS chunks, global_load_lds(16B).
// grid: (M/64, N/64, batch)
// ---------------------------------------------------------------------------
__global__ __launch_bounds__(256)
void gemm_bf16(const us* __restrict__ A, const us* __restrict__ Bt,
               const float* __restrict__ bias, void* __restrict__ Cv,
               int K, int ldC, long strideB, int strideBias, long strideC,
               int outBf16)
{
    __shared__ us As[64 * 64];
    __shared__ us Bs[64 * 64];
    const int b = blockIdx.z;
    const us* Bb = Bt + (size_t)b * strideB;
    const float* biasb = bias + (size_t)b * strideBias;
    const int row0 = blockIdx.x << 6, col0 = blockIdx.y << 6;
    const int tid = threadIdx.x, wave = tid >> 6, lane = tid & 63;
    const int m = lane & 15, quad = lane >> 4;
    const int sr = lane >> 3;                  // staging: row within 8-row group
    const int scs = (lane & 7) ^ sr;           // swizzled source chunk

    f32x4_t z = {0.f, 0.f, 0.f, 0.f};
    f32x4_t acc[4] = {z, z, z, z};

    for (int k0 = 0; k0 < K; k0 += 64) {
#pragma unroll
        for (int t = 0; t < 2; t++) {
            const int rl = wave * 16 + t * 8 + sr;
            load16(&As[(wave * 16 + t * 8) * 64], A  + (size_t)(row0 + rl) * K + k0 + scs * 8);
            load16(&Bs[(wave * 16 + t * 8) * 64], Bb + (size_t)(col0 + rl) * K + k0 + scs * 8);
        }
        __syncthreads();
#pragma unroll
        for (int ks = 0; ks < 2; ks++) {
            const int slot = ((ks * 4 + quad) ^ (m & 7)) * 8;
            bf16x8_t a = *(const bf16x8_t*)&As[(wave * 16 + m) * 64 + slot];
#pragma unroll
            for (int t = 0; t < 4; t++) {
                bf16x8_t bb = *(const bf16x8_t*)&Bs[(t * 16 + m) * 64 + slot];
                acc[t] = __builtin_amdgcn_mfma_f32_16x16x32_bf16(a, bb, acc[t], 0, 0, 0);
            }
        }
        __syncthreads();
    }

    // C/D layout: col = lane&15, row = quad*4 + reg   [m89-verified]
    const int rbase = row0 + wave * 16 + quad * 4;
    if (outBf16) {
        us* Cb = (us*)Cv + (size_t)b * strideC;
#pragma unroll
        for (int t = 0; t < 4; t++) {
            const int col = col0 + t * 16 + m;
            const float bi = biasb[col];
#pragma unroll
            for (int r = 0; r < 4; r++)
                Cb[(size_t)(rbase + r) * ldC + col] = f2b(acc[t][r] + bi);
        }
    } else {
        float* Cb = (float*)Cv + (size_t)b * strideC;
#pragma unroll
        for (int t = 0; t < 4; t++) {
            const int col = col0 + t * 16 + m;
            const float bi = biasb[col];
#pragma unroll
            for (int r = 0; r < 4; r++)
                Cb[(size_t)(rbase + r) * ldC + col] = acc[t][r] + bi;
        }
    }
}

// ---------------------------------------------------------------------------
// Banded attention, one wave per (h,b,l). bf16 q/k/v in, bf16 out.
// Scores: per-lane partials + 64-lane butterfly multi-reduce (lane holds
// score for k = bitrev5(lane&31)); resample via 32 const-lane broadcasts.
// ---------------------------------------------------------------------------
__global__ __launch_bounds__(256)
void attn_kernel(const us* __restrict__ qb, const us* __restrict__ kb,
                 const us* __restrict__ vb, const float* __restrict__ Ws,
                 const float* __restrict__ bs, us* __restrict__ ab)
{
    const int wave = threadIdx.x >> 6;
    const int lane = threadIdx.x & 63;
    const long pos = (long)blockIdx.x * 4 + wave;   // h*8192 + b*4096 + l
    const int h  = (int)(pos >> 13);
    const int ml = (int)(pos & 8191);
    const int l  = ml & 4095;
    const int sub = (h < 5) ? 0 : (h < 10) ? 1 : (h < 12) ? 2 : (h == 12) ? 3 : 4;
    const int dil = (sub <= 1) ? 1 : (1 << (sub - 1));   // 1,1,2,4,8

    const float qv = b2f(qb[((size_t)sub * M_ROWS + ml) * 64 + lane]);
    const us* kbase = kb + ((size_t)sub * M_ROWS + (ml - l)) * 64;

    float p[KW];
#pragma unroll
    for (int k = 0; k < KW; k++) {
        int src = l + (k - 16) * dil;
        src = src < 0 ? 0 : (src > L_SEQ - 1 ? L_SEQ - 1 : src);
        p[k] = qv * b2f(kbase[(size_t)src * 64 + lane]);
    }

    // butterfly multi-value reduction: 32 values over 64 lanes
#pragma unroll
    for (int s = 0; s < 5; s++) {
        const int off  = 1 << s;
        const int half = 16 >> s;
        const int bit  = (lane >> s) & 1;
#pragma unroll
        for (int r = 0; r < half; r++) {
            float send = bit ? p[r] : p[r + half];
            float recv = __shfl_xor(send, off, 64);
            p[r] = (bit ? p[r + half] : p[r]) + recv;
        }
    }
    // lane now holds score for k = bitrev5(lane&31); fold lanes l and l+32
    float sck = (p[0] + __shfl_xor(p[0], 32, 64)) * 0.125f;   // /sqrt(64)

    // positional resampling: lane computes m = lane&31 (both halves identical)
    const int mcol = lane & 31;
    const float* wsrow = Ws + (size_t)h * KW * KW;
    float smp = bs[h * KW + mcol];
#pragma unroll
    for (int k = 0; k < KW; k++) {
        const int srcLane = ((k & 1) << 4) | ((k & 2) << 2) | (k & 4) |
                            ((k & 8) >> 2) | ((k & 16) >> 4);   // bitrev5(k)
        float v = __shfl(sck, srcLane, 64);
        smp += v * wsrow[k * KW + mcol];
    }

    // softmax over 32 (xor 16..1 stays within each half-wave)
    float mx = smp;
#pragma unroll
    for (int off = 16; off > 0; off >>= 1) mx = fmaxf(mx, __shfl_xor(mx, off, 64));
    float ex = __expf(smp - mx);
    float sum = ex;
#pragma unroll
    for (int off = 16; off > 0; off >>= 1) sum += __shfl_xor(sum, off, 64);
    const float attn = ex / sum;

    // PV: lane i accumulates over window positions; attn broadcast from lane m
    const us* vbase = vb + ((size_t)h * M_ROWS + (ml - l)) * 64;
    float o = 0.f;
#pragma unroll
    for (int mm = 0; mm < KW; mm++) {
        float am = __shfl(attn, mm, 64);
        int src = l + (mm - 16) * dil;
        src = src < 0 ? 0 : (src > L_SEQ - 1 ? L_SEQ - 1 : src);
        o += am * b2f(vbase[(size_t)src * 64 + lane]);
    }

    ab[(size_t)ml * N_CAT + h * 64 + lane] = f2b(o);
}

// ---------------------------------------------------------------------------
extern "C" void kernel_launch(void* const* d_in, const int* in_sizes, int n_in,
                              void* d_out, int out_size, void* d_ws, size_t ws_size,
                              hipStream_t stream)
{
    const float* query = (const float*)d_in[0];
    const float* key   = (const float*)d_in[1];
    const float* value = (const float*)d_in[2];
    const float* Wq    = (const float*)d_in[3];
    const float* bq    = (const float*)d_in[4];
    const float* Wk    = (const float*)d_in[5];
    const float* bk    = (const float*)d_in[6];
    const float* Wv    = (const float*)d_in[7];
    const float* bv    = (const float*)d_in[8];
    const float* Ws    = (const float*)d_in[9];
    const float* bs    = (const float*)d_in[10];
    const float* Wc    = (const float*)d_in[11];
    const float* bc    = (const float*)d_in[12];
    float* out = (float*)d_out;

    // workspace carve (bf16 elements). ab aliases Xq (disjoint lifetimes:
    // Xq last read by proj-q gemm; ab first written by attn afterwards).
    us* w = (us*)d_ws;
    us* Xq  = w;                         // 8192*1024
    us* ab  = w;                         // 8192*896   (alias)
    us* Xk  = Xq  + (size_t)M_ROWS * D_MODEL;
    us* Xv  = Xk  + (size_t)M_ROWS * D_MODEL;
    us* Wqt = Xv  + (size_t)M_ROWS * D_MODEL;          // 5*64*1024
    us* Wkt = Wqt + (size_t)SUBHEADS * D_INT * D_MODEL;
    us* Wvt = Wkt + (size_t)SUBHEADS * D_INT * D_MODEL; // 14*64*1024
    us* Wct = Wvt + (size_t)HEADS * D_INT * D_MODEL;    // 1024*896
    us* qbuf = Wct + (size_t)D_MODEL * N_CAT;           // 5*8192*64
    us* kbuf = qbuf + (size_t)SUBHEADS * M_ROWS * D_INT;
    us* vbuf = kbuf + (size_t)SUBHEADS * M_ROWS * D_INT; // 14*8192*64

    const int n4 = M_ROWS * D_MODEL / 4;   // 2,097,152
    cast_bf16<<<dim3(n4 / 256), dim3(256), 0, stream>>>((const float4*)query, Xq, n4);
    cast_bf16<<<dim3(n4 / 256), dim3(256), 0, stream>>>((const float4*)key,   Xk, n4);
    cast_bf16<<<dim3(n4 / 256), dim3(256), 0, stream>>>((const float4*)value, Xv, n4);

    {
        int tq = SUBHEADS * D_MODEL * D_INT;   // 327,680
        tcast<<<dim3((tq + 255) / 256), dim3(256), 0, stream>>>(Wq, Wqt, D_MODEL, D_INT, tq);
        tcast<<<dim3((tq + 255) / 256), dim3(256), 0, stream>>>(Wk, Wkt, D_MODEL, D_INT, tq);
        int tv = HEADS * D_MODEL * D_INT;      // 917,504
        tcast<<<dim3((tv + 255) / 256), dim3(256), 0, stream>>>(Wv, Wvt, D_MODEL, D_INT, tv);
        int tc = N_CAT * D_MODEL;              // 917,504
        tcast<<<dim3((tc + 255) / 256), dim3(256), 0, stream>>>(Wc, Wct, N_CAT, D_MODEL, tc);
    }

    dim3 blk(256);
    // q,k projections: M=8192, N=64, K=1024, batch=5; bf16 out
    gemm_bf16<<<dim3(M_ROWS / 64, 1, SUBHEADS), blk, 0, stream>>>(
        Xq, Wqt, bq, qbuf, D_MODEL, D_INT,
        (long)D_INT * D_MODEL, D_INT, (long)M_ROWS * D_INT, 1);
    gemm_bf16<<<dim3(M_ROWS / 64, 1, SUBHEADS), blk, 0, stream>>>(
        Xk, Wkt, bk, kbuf, D_MODEL, D_INT,
        (long)D_INT * D_MODEL, D_INT, (long)M_ROWS * D_INT, 1);
    // v projection: batch=14
    gemm_bf16<<<dim3(M_ROWS / 64, 1, HEADS), blk, 0, stream>>>(
        Xv, Wvt, bv, vbuf, D_MODEL, D_INT,
        (long)D_INT * D_MODEL, D_INT, (long)M_ROWS * D_INT, 1);

    const long npos = (long)HEADS * M_ROWS;
    attn_kernel<<<dim3((unsigned)(npos / 4)), blk, 0, stream>>>(qbuf, kbuf, vbuf, Ws, bs, ab);

    // out gemm: M=8192, N=1024, K=896, fp32 out
    gemm_bf16<<<dim3(M_ROWS / 64, D_MODEL / 64, 1), blk, 0, stream>>>(
        ab, Wct, bc, out, N_CAT, D_MODEL, 0, 0, 0, 0);
}

// Round 3
// 426.026 us; speedup vs baseline: 2.6499x; 2.6499x over previous
//
#include <hip/hip_runtime.h>
#include <math.h>

#define D_MODEL 1024
#define D_INT   64
#define KW      32
#define L_SEQ   4096
#define SUBHEADS 5
#define HEADS   14
#define M_ROWS  8192
#define N_CAT   896

typedef unsigned short us;
typedef __attribute__((ext_vector_type(8))) short bf16x8_t;
typedef __attribute__((ext_vector_type(4))) float f32x4_t;

__device__ __forceinline__ float b2f(us x) {
    unsigned int u = ((unsigned int)x) << 16;
    float f; __builtin_memcpy(&f, &u, 4); return f;
}
__device__ __forceinline__ us f2b(float f) {
    unsigned int u; __builtin_memcpy(&u, &f, 4);
    u += 0x7fffu + ((u >> 16) & 1u);
    return (us)(u >> 16);
}
__device__ __forceinline__ void load16(void* lds, const void* g) {
    __builtin_amdgcn_global_load_lds(
        (const __attribute__((address_space(1))) unsigned int*)g,
        (__attribute__((address_space(3))) unsigned int*)lds, 16, 0, 0);
}
__device__ __forceinline__ int subhead_of(int h) {
    return (h < 5) ? 0 : (h < 10) ? 1 : (h < 12) ? 2 : (h == 12) ? 3 : 4;
}
__device__ __forceinline__ int dil_of_sub(int s) {
    return (s <= 1) ? 1 : (1 << (s - 1));   // 1,1,2,4,8
}

// ---------------------------------------------------------------------------
// fp32 -> bf16 elementwise cast
// ---------------------------------------------------------------------------
__global__ __launch_bounds__(256)
void cast_bf16(const float4* __restrict__ s, us* __restrict__ d, int n4)
{
    int i = blockIdx.x * 256 + threadIdx.x;
    if (i >= n4) return;
    float4 v = s[i];
    ushort4 o;
    o.x = f2b(v.x); o.y = f2b(v.y); o.z = f2b(v.z); o.w = f2b(v.w);
    ((ushort4*)d)[i] = o;
}

// ---------------------------------------------------------------------------
// transpose + cast: dst[b][n][k] = src[b][k][n]
// ---------------------------------------------------------------------------
__global__ __launch_bounds__(256)
void tcast(const float* __restrict__ s, us* __restrict__ d, int K, int N, int total)
{
    for (int idx = blockIdx.x * 256 + threadIdx.x; idx < total; idx += gridDim.x * 256) {
        int k = idx % K;
        int t = idx / K;
        int n = t % N;
        int b = t / N;
        d[idx] = f2b(s[((size_t)b * K + k) * N + n]);
    }
}

// ---------------------------------------------------------------------------
// bf16 MFMA GEMM (64x64 tile, BK=64, XOR-swizzled LDS, global_load_lds 16B)
// ---------------------------------------------------------------------------
__global__ __launch_bounds__(256)
void gemm_bf16(const us* __restrict__ A, const us* __restrict__ Bt,
               const float* __restrict__ bias, void* __restrict__ Cv,
               int K, int ldC, long strideB, int strideBias, long strideC,
               int outBf16)
{
    __shared__ us As[64 * 64];
    __shared__ us Bs[64 * 64];
    const int b = blockIdx.z;
    const us* Bb = Bt + (size_t)b * strideB;
    const float* biasb = bias + (size_t)b * strideBias;
    const int row0 = blockIdx.x << 6, col0 = blockIdx.y << 6;
    const int tid = threadIdx.x, wave = tid >> 6, lane = tid & 63;
    const int m = lane & 15, quad = lane >> 4;
    const int sr = lane >> 3;
    const int scs = (lane & 7) ^ sr;

    f32x4_t z = {0.f, 0.f, 0.f, 0.f};
    f32x4_t acc[4] = {z, z, z, z};

    for (int k0 = 0; k0 < K; k0 += 64) {
#pragma unroll
        for (int t = 0; t < 2; t++) {
            const int rl = wave * 16 + t * 8 + sr;
            load16(&As[(wave * 16 + t * 8) * 64], A  + (size_t)(row0 + rl) * K + k0 + scs * 8);
            load16(&Bs[(wave * 16 + t * 8) * 64], Bb + (size_t)(col0 + rl) * K + k0 + scs * 8);
        }
        __syncthreads();
#pragma unroll
        for (int ks = 0; ks < 2; ks++) {
            const int slot = ((ks * 4 + quad) ^ (m & 7)) * 8;
            bf16x8_t a = *(const bf16x8_t*)&As[(wave * 16 + m) * 64 + slot];
#pragma unroll
            for (int t = 0; t < 4; t++) {
                bf16x8_t bb = *(const bf16x8_t*)&Bs[(t * 16 + m) * 64 + slot];
                acc[t] = __builtin_amdgcn_mfma_f32_16x16x32_bf16(a, bb, acc[t], 0, 0, 0);
            }
        }
        __syncthreads();
    }

    const int rbase = row0 + wave * 16 + quad * 4;
    if (outBf16) {
        us* Cb = (us*)Cv + (size_t)b * strideC;
#pragma unroll
        for (int t = 0; t < 4; t++) {
            const int col = col0 + t * 16 + m;
            const float bi = biasb[col];
#pragma unroll
            for (int r = 0; r < 4; r++)
                Cb[(size_t)(rbase + r) * ldC + col] = f2b(acc[t][r] + bi);
        }
    } else {
        float* Cb = (float*)Cv + (size_t)b * strideC;
#pragma unroll
        for (int t = 0; t < 4; t++) {
            const int col = col0 + t * 16 + m;
            const float bi = biasb[col];
#pragma unroll
            for (int r = 0; r < 4; r++)
                Cb[(size_t)(rbase + r) * ldC + col] = acc[t][r] + bi;
        }
    }
}

// ---------------------------------------------------------------------------
// Kernel A: banded scores PER SUBHEAD (5x fewer than per-head).
// One wave per (s, b, l); lane = channel. Serial shfl_xor reduce per window
// position (R1-proven pattern, no register arrays). scores: [S][8192][KW] f32.
// grid: (2048, 5), block 256.
// ---------------------------------------------------------------------------
__global__ __launch_bounds__(256)
void score_kernel(const us* __restrict__ qb, const us* __restrict__ kb,
                  float* __restrict__ scores)
{
    const int wave = threadIdx.x >> 6;
    const int lane = threadIdx.x & 63;
    const int s    = blockIdx.y;
    const int ml   = blockIdx.x * 4 + wave;
    const int l    = ml & 4095;
    const int dil  = dil_of_sub(s);

    const float qv = b2f(qb[((size_t)s * M_ROWS + ml) * 64 + lane]);
    const us* kbase = kb + ((size_t)s * M_ROWS + (ml - l)) * 64;
    const int lk = lane & 31;

    float msc = 0.f;
#pragma unroll
    for (int k = 0; k < KW; k++) {
        int src = l + (k - 16) * dil;
        src = src < 0 ? 0 : (src > L_SEQ - 1 ? L_SEQ - 1 : src);
        float p = qv * b2f(kbase[(size_t)src * 64 + lane]);
#pragma unroll
        for (int off = 32; off > 0; off >>= 1) p += __shfl_xor(p, off, 64);
        msc = (lk == k) ? p * 0.125f : msc;
    }
    if (lane < 32)
        scores[((size_t)s * M_ROWS + ml) * KW + lane] = msc;
}

// ---------------------------------------------------------------------------
// Kernel B: per-head resample + softmax + PV. One wave per (h, b, l).
// Ws[h] staged in LDS; score/attn broadcast via tiny LDS buffers (no wide
// shuffles, no register arrays).
// grid: (2048, 14), block 256.
// ---------------------------------------------------------------------------
__global__ __launch_bounds__(256)
void head_kernel(const float* __restrict__ scores, const us* __restrict__ vb,
                 const float* __restrict__ Ws, const float* __restrict__ bs,
                 us* __restrict__ ab)
{
    __shared__ float wsl[KW * KW];     // [k][m], stride 32: lane m -> bank m
    __shared__ float bsl[KW];
    __shared__ float scb[4][KW];
    __shared__ float atb[4][KW];

    const int tid  = threadIdx.x;
    const int wave = tid >> 6;
    const int lane = tid & 63;
    const int h    = blockIdx.y;
    const int s    = subhead_of(h);
    const int dil  = dil_of_sub(s);
    const int ml   = blockIdx.x * 4 + wave;
    const int l    = ml & 4095;
    const int mi   = lane & 31;

    ((float4*)wsl)[tid] = ((const float4*)(Ws + (size_t)h * KW * KW))[tid & 255];
    if (tid < KW) bsl[tid] = bs[h * KW + tid];

    const float sc = scores[((size_t)s * M_ROWS + ml) * KW + mi];
    __syncthreads();
    if (lane < 32) scb[wave][lane] = sc;
    __syncthreads();

    // resample: lane computes column mi (halves duplicate)
    float acc = bsl[mi];
#pragma unroll
    for (int k = 0; k < KW; k++)
        acc += scb[wave][k] * wsl[k * KW + mi];

    // softmax over 32 (xor 16..1 stays in each half-wave)
    float mx = acc;
#pragma unroll
    for (int off = 16; off > 0; off >>= 1) mx = fmaxf(mx, __shfl_xor(mx, off, 64));
    float ex = __expf(acc - mx);
    float sum = ex;
#pragma unroll
    for (int off = 16; off > 0; off >>= 1) sum += __shfl_xor(sum, off, 64);
    const float at = ex / sum;

    if (lane < 32) atb[wave][lane] = at;
    __syncthreads();

    // PV: lane = output channel
    const us* vbase = vb + ((size_t)h * M_ROWS + (ml - l)) * 64;
    float o = 0.f;
#pragma unroll
    for (int mm = 0; mm < KW; mm++) {
        int src = l + (mm - 16) * dil;
        src = src < 0 ? 0 : (src > L_SEQ - 1 ? L_SEQ - 1 : src);
        o += atb[wave][mm] * b2f(vbase[(size_t)src * 64 + lane]);
    }
    ab[(size_t)ml * N_CAT + h * 64 + lane] = f2b(o);
}

// ---------------------------------------------------------------------------
extern "C" void kernel_launch(void* const* d_in, const int* in_sizes, int n_in,
                              void* d_out, int out_size, void* d_ws, size_t ws_size,
                              hipStream_t stream)
{
    const float* query = (const float*)d_in[0];
    const float* key   = (const float*)d_in[1];
    const float* value = (const float*)d_in[2];
    const float* Wq    = (const float*)d_in[3];
    const float* bq    = (const float*)d_in[4];
    const float* Wk    = (const float*)d_in[5];
    const float* bk    = (const float*)d_in[6];
    const float* Wv    = (const float*)d_in[7];
    const float* bv    = (const float*)d_in[8];
    const float* Ws    = (const float*)d_in[9];
    const float* bs    = (const float*)d_in[10];
    const float* Wc    = (const float*)d_in[11];
    const float* bc    = (const float*)d_in[12];
    float* out = (float*)d_out;

    // workspace carve (bf16 elements). Aliases with disjoint lifetimes:
    //   ab     aliases Xq (Xq dead after q-proj gemm)
    //   scores aliases Xk (Xk dead after k-proj gemm)
    us* w = (us*)d_ws;
    us* Xq  = w;                          // 8192*1024
    us* ab  = w;                          // 8192*896   (alias of Xq)
    us* Xk  = Xq  + (size_t)M_ROWS * D_MODEL;
    float* scores = (float*)Xk;           // 5*8192*32 f32 (alias of Xk)
    us* Xv  = Xk  + (size_t)M_ROWS * D_MODEL;
    us* Wqt = Xv  + (size_t)M_ROWS * D_MODEL;
    us* Wkt = Wqt + (size_t)SUBHEADS * D_INT * D_MODEL;
    us* Wvt = Wkt + (size_t)SUBHEADS * D_INT * D_MODEL;
    us* Wct = Wvt + (size_t)HEADS * D_INT * D_MODEL;
    us* qbuf = Wct + (size_t)D_MODEL * N_CAT;
    us* kbuf = qbuf + (size_t)SUBHEADS * M_ROWS * D_INT;
    us* vbuf = kbuf + (size_t)SUBHEADS * M_ROWS * D_INT;

    const int n4 = M_ROWS * D_MODEL / 4;
    cast_bf16<<<dim3(n4 / 256), dim3(256), 0, stream>>>((const float4*)query, Xq, n4);
    cast_bf16<<<dim3(n4 / 256), dim3(256), 0, stream>>>((const float4*)key,   Xk, n4);
    cast_bf16<<<dim3(n4 / 256), dim3(256), 0, stream>>>((const float4*)value, Xv, n4);

    {
        int tq = SUBHEADS * D_MODEL * D_INT;
        tcast<<<dim3((tq + 255) / 256), dim3(256), 0, stream>>>(Wq, Wqt, D_MODEL, D_INT, tq);
        tcast<<<dim3((tq + 255) / 256), dim3(256), 0, stream>>>(Wk, Wkt, D_MODEL, D_INT, tq);
        int tv = HEADS * D_MODEL * D_INT;
        tcast<<<dim3((tv + 255) / 256), dim3(256), 0, stream>>>(Wv, Wvt, D_MODEL, D_INT, tv);
        int tc = N_CAT * D_MODEL;
        tcast<<<dim3((tc + 255) / 256), dim3(256), 0, stream>>>(Wc, Wct, N_CAT, D_MODEL, tc);
    }

    dim3 blk(256);
    gemm_bf16<<<dim3(M_ROWS / 64, 1, SUBHEADS), blk, 0, stream>>>(
        Xq, Wqt, bq, qbuf, D_MODEL, D_INT,
        (long)D_INT * D_MODEL, D_INT, (long)M_ROWS * D_INT, 1);
    gemm_bf16<<<dim3(M_ROWS / 64, 1, SUBHEADS), blk, 0, stream>>>(
        Xk, Wkt, bk, kbuf, D_MODEL, D_INT,
        (long)D_INT * D_MODEL, D_INT, (long)M_ROWS * D_INT, 1);
    gemm_bf16<<<dim3(M_ROWS / 64, 1, HEADS), blk, 0, stream>>>(
        Xv, Wvt, bv, vbuf, D_MODEL, D_INT,
        (long)D_INT * D_MODEL, D_INT, (long)M_ROWS * D_INT, 1);

    score_kernel<<<dim3(M_ROWS / 4, SUBHEADS), blk, 0, stream>>>(qbuf, kbuf, scores);
    head_kernel<<<dim3(M_ROWS / 4, HEADS), blk, 0, stream>>>(scores, vbuf, Ws, bs, ab);

    gemm_bf16<<<dim3(M_ROWS / 64, D_MODEL / 64, 1), blk, 0, stream>>>(
        ab, Wct, bc, out, N_CAT, D_MODEL, 0, 0, 0, 0);
}

// Round 4
// 320.069 us; speedup vs baseline: 3.5271x; 1.3310x over previous
//
#include <hip/hip_runtime.h>
#include <math.h>

#define D_MODEL 1024
#define D_INT   64
#define KW      32
#define L_SEQ   4096
#define SUBHEADS 5
#define HEADS   14
#define M_ROWS  8192
#define N_CAT   896
#define NQK     320          // SUBHEADS*64
#define WMAX    312          // 64 + 31*8 (max slab rows, d=8)

typedef unsigned short us;
typedef unsigned int   uu;
typedef __attribute__((ext_vector_type(8))) short bf16x8_t;
typedef __attribute__((ext_vector_type(4))) float f32x4_t;

__device__ __forceinline__ float u2f(uu u) {
    float f; __builtin_memcpy(&f, &u, 4); return f;
}
__device__ __forceinline__ us f2b(float f) {
    uu u; __builtin_memcpy(&u, &f, 4);
    u += 0x7fffu + ((u >> 16) & 1u);
    return (us)(u >> 16);
}
__device__ __forceinline__ void load16(void* lds, const void* g) {
    __builtin_amdgcn_global_load_lds(
        (const __attribute__((address_space(1))) unsigned int*)g,
        (__attribute__((address_space(3))) unsigned int*)lds, 16, 0, 0);
}
__device__ __forceinline__ int subhead_of(int h) {
    return (h < 5) ? 0 : (h < 10) ? 1 : (h < 12) ? 2 : (h == 12) ? 3 : 4;
}
__device__ __forceinline__ int dil_of_sub(int s) {
    return (s <= 1) ? 1 : (1 << (s - 1));   // 1,1,2,4,8
}

// ---------------------------------------------------------------------------
// fp32 -> bf16 elementwise cast
// ---------------------------------------------------------------------------
__global__ __launch_bounds__(256)
void cast_bf16(const float4* __restrict__ s, us* __restrict__ d, int n4)
{
    int i = blockIdx.x * 256 + threadIdx.x;
    if (i >= n4) return;
    float4 v = s[i];
    ushort4 o;
    o.x = f2b(v.x); o.y = f2b(v.y); o.z = f2b(v.z); o.w = f2b(v.w);
    ((ushort4*)d)[i] = o;
}

// ---------------------------------------------------------------------------
// transpose + cast: dst[b][n][k] = src[b][k][n]
// ---------------------------------------------------------------------------
__global__ __launch_bounds__(256)
void tcast(const float* __restrict__ s, us* __restrict__ d, int K, int N, int total)
{
    for (int idx = blockIdx.x * 256 + threadIdx.x; idx < total; idx += gridDim.x * 256) {
        int k = idx % K;
        int t = idx / K;
        int n = t % N;
        int b = t / N;
        d[idx] = f2b(s[((size_t)b * K + k) * N + n]);
    }
}

// ---------------------------------------------------------------------------
// bf16 MFMA GEMM, 128x64 tile, BK=64. A:[8192][K], Bt:[N][K], C:[8192][ldC].
// grid (64, N/64). Wave w: rows w*32..w*32+31 (2 m-tiles), all 64 cols.
// ---------------------------------------------------------------------------
__global__ __launch_bounds__(256)
void gemm_bf16(const us* __restrict__ A, const us* __restrict__ Bt,
               const float* __restrict__ bias, void* __restrict__ Cv,
               int K, int ldC, int outBf16)
{
    __shared__ us As[128 * 64];
    __shared__ us Bs[64 * 64];
    const int row0 = blockIdx.x << 7, col0 = blockIdx.y << 6;
    const int tid = threadIdx.x, w = tid >> 6, lane = tid & 63;
    const int m = lane & 15, quad = lane >> 4;
    const int sr = lane >> 3;                  // 8-row group row
    const int scs = (lane & 7) ^ sr;           // swizzled source chunk

    f32x4_t z = {0.f, 0.f, 0.f, 0.f};
    f32x4_t acc[2][4] = {{z, z, z, z}, {z, z, z, z}};

    for (int k0 = 0; k0 < K; k0 += 64) {
#pragma unroll
        for (int p = 0; p < 4; p++) {
            const int r = w * 32 + p * 8 + sr;
            load16(&As[(w * 32 + p * 8) * 64], A + (size_t)(row0 + r) * K + k0 + scs * 8);
        }
#pragma unroll
        for (int p = 0; p < 2; p++) {
            const int r = w * 16 + p * 8 + sr;
            load16(&Bs[(w * 16 + p * 8) * 64], Bt + (size_t)(col0 + r) * K + k0 + scs * 8);
        }
        __syncthreads();
#pragma unroll
        for (int ks = 0; ks < 2; ks++) {
            const int slot = ((ks * 4 + quad) ^ (m & 7)) * 8;
            bf16x8_t a0 = *(const bf16x8_t*)&As[(w * 32 + m) * 64 + slot];
            bf16x8_t a1 = *(const bf16x8_t*)&As[(w * 32 + 16 + m) * 64 + slot];
#pragma unroll
            for (int t = 0; t < 4; t++) {
                bf16x8_t bb = *(const bf16x8_t*)&Bs[(t * 16 + m) * 64 + slot];
                acc[0][t] = __builtin_amdgcn_mfma_f32_16x16x32_bf16(a0, bb, acc[0][t], 0, 0, 0);
                acc[1][t] = __builtin_amdgcn_mfma_f32_16x16x32_bf16(a1, bb, acc[1][t], 0, 0, 0);
            }
        }
        __syncthreads();
    }

    // C/D layout: col = lane&15, row = quad*4 + reg
#pragma unroll
    for (int tm = 0; tm < 2; tm++) {
        const int rbase = row0 + w * 32 + tm * 16 + quad * 4;
        if (outBf16) {
            us* Cb = (us*)Cv;
#pragma unroll
            for (int t = 0; t < 4; t++) {
                const int col = col0 + t * 16 + m;
                const float bi = bias[col];
#pragma unroll
                for (int r = 0; r < 4; r++)
                    Cb[(size_t)(rbase + r) * ldC + col] = f2b(acc[tm][t][r] + bi);
            }
        } else {
            float* Cb = (float*)Cv;
#pragma unroll
            for (int t = 0; t < 4; t++) {
                const int col = col0 + t * 16 + m;
                const float bi = bias[col];
#pragma unroll
                for (int r = 0; r < 4; r++)
                    Cb[(size_t)(rbase + r) * ldC + col] = acc[tm][t][r] + bi;
            }
        }
    }
}

// ---------------------------------------------------------------------------
// Score kernel: block = (64 positions, subhead). Lane = window index (j),
// half-wave = position parity. K rows staged pre-clamped into LDS slab
// (33-dword padded rows); per-lane column rotation kills bank conflicts.
// scores: [S][8192][32] f32.  grid (128, 5).
// ---------------------------------------------------------------------------
__global__ __launch_bounds__(256)
void score_kernel(const us* __restrict__ qb, const us* __restrict__ kb,
                  float* __restrict__ scores)
{
    __shared__ uu kslab[WMAX * 33];
    __shared__ uu qslab[64 * 32];

    const int tid  = threadIdx.x;
    const int wave = tid >> 6;
    const int lane = tid & 63;
    const int j    = lane & 31;
    const int half = lane >> 5;
    const int s    = blockIdx.y;
    const int d    = dil_of_sub(s);
    const int ml0  = blockIdx.x * 64;
    const int l0   = ml0 & 4095;
    const int bm   = ml0 - l0;            // batch base row
    const int W    = 64 + 31 * d;

    const uu* kg = (const uu*)kb;
    const uu* qg = (const uu*)qb;

    for (int idx = tid; idx < W * 32; idx += 256) {
        int r = idx >> 5, c = idx & 31;
        int src = l0 - 16 * d + r;
        src = src < 0 ? 0 : (src > 4095 ? 4095 : src);
        kslab[r * 33 + c] = kg[(size_t)(bm + src) * 160 + s * 32 + c];
    }
    for (int idx = tid; idx < 64 * 32; idx += 256) {
        int r = idx >> 5, c = idx & 31;
        qslab[r * 32 + c] = qg[(size_t)(ml0 + r) * 160 + s * 32 + c];
    }
    __syncthreads();

#pragma unroll
    for (int i = 0; i < 8; i++) {
        const int p = wave * 16 + i * 2 + half;     // position within block
        const uu* krow = kslab + (p + j * d) * 33;
        const uu* qrow = qslab + p * 32;
        float acc = 0.f;
#pragma unroll
        for (int c = 0; c < 32; c++) {
            const int cc = (c + j) & 31;            // rotation: conflict-free
            uu kd = krow[cc];
            uu qd = qrow[cc];
            acc = fmaf(u2f(kd << 16), u2f(qd << 16), acc);
            acc = fmaf(u2f(kd & 0xffff0000u), u2f(qd & 0xffff0000u), acc);
        }
        scores[((size_t)s * M_ROWS + ml0 + p) * 32 + j] = acc * 0.125f;
    }
}

// ---------------------------------------------------------------------------
// Head kernel: block = (64 positions, head). Lane = channel-pair j for its
// half's position. V slab in LDS (pre-clamped); Ws column in 32 registers;
// score/attn all-to-all via per-wave LDS rows.  grid (128, 14).
// ---------------------------------------------------------------------------
__global__ __launch_bounds__(256)
void head_kernel(const float* __restrict__ scores, const us* __restrict__ vb,
                 const float* __restrict__ Ws, const float* __restrict__ bs,
                 us* __restrict__ ab)
{
    __shared__ uu vslab[WMAX * 33];
    __shared__ float scb[8 * 32];
    __shared__ float atb[8 * 32];

    const int tid  = threadIdx.x;
    const int wave = tid >> 6;
    const int lane = tid & 63;
    const int j    = lane & 31;
    const int half = lane >> 5;
    const int h    = blockIdx.y;
    const int s    = subhead_of(h);
    const int d    = dil_of_sub(s);
    const int ml0  = blockIdx.x * 64;
    const int l0   = ml0 & 4095;
    const int bm   = ml0 - l0;
    const int W    = 64 + 31 * d;

    const uu* vg = (const uu*)vb;
    for (int idx = tid; idx < W * 32; idx += 256) {
        int r = idx >> 5, c = idx & 31;
        int src = l0 - 16 * d + r;
        src = src < 0 ? 0 : (src > 4095 ? 4095 : src);
        vslab[r * 33 + c] = vg[(size_t)(bm + src) * 448 + h * 32 + c];
    }

    float wsr[32];
#pragma unroll
    for (int k = 0; k < 32; k++) wsr[k] = Ws[(size_t)h * 1024 + k * 32 + j];
    const float bsv = bs[h * 32 + j];
    __syncthreads();

    const int rowid = wave * 2 + half;

#pragma unroll
    for (int i = 0; i < 8; i++) {
        const int p  = wave * 16 + i * 2 + half;
        const int ml = ml0 + p;

        float sc = scores[((size_t)s * M_ROWS + ml) * 32 + j];
        scb[rowid * 32 + j] = sc;
        const float* scrow = scb + rowid * 32;
        float acc = bsv;
#pragma unroll
        for (int k = 0; k < 32; k++) acc = fmaf(scrow[k], wsr[k], acc);

        // softmax over 32 (xor 16..1 stays within each half-wave)
        float mx = acc;
#pragma unroll
        for (int off = 16; off > 0; off >>= 1) mx = fmaxf(mx, __shfl_xor(mx, off, 64));
        float ex = __expf(acc - mx);
        float sum = ex;
#pragma unroll
        for (int off = 16; off > 0; off >>= 1) sum += __shfl_xor(sum, off, 64);
        const float at = ex / sum;

        atb[rowid * 32 + j] = at;
        const float* atrow = atb + rowid * 32;

        float o0 = 0.f, o1 = 0.f;
        const uu* vrow = vslab + p * 33 + j;
#pragma unroll
        for (int mm = 0; mm < 32; mm++) {
            float a = atrow[mm];
            uu vd = vrow[mm * d * 33];
            o0 = fmaf(u2f(vd << 16), a, o0);
            o1 = fmaf(u2f(vd & 0xffff0000u), a, o1);
        }
        uu od = (uu)f2b(o0) | ((uu)f2b(o1) << 16);
        ((uu*)ab)[(size_t)ml * 448 + h * 32 + j] = od;
    }
}

// ---------------------------------------------------------------------------
extern "C" void kernel_launch(void* const* d_in, const int* in_sizes, int n_in,
                              void* d_out, int out_size, void* d_ws, size_t ws_size,
                              hipStream_t stream)
{
    const float* query = (const float*)d_in[0];
    const float* key   = (const float*)d_in[1];
    const float* value = (const float*)d_in[2];
    const float* Wq    = (const float*)d_in[3];
    const float* bq    = (const float*)d_in[4];
    const float* Wk    = (const float*)d_in[5];
    const float* bk    = (const float*)d_in[6];
    const float* Wv    = (const float*)d_in[7];
    const float* bv    = (const float*)d_in[8];
    const float* Ws    = (const float*)d_in[9];
    const float* bs    = (const float*)d_in[10];
    const float* Wc    = (const float*)d_in[11];
    const float* bc    = (const float*)d_in[12];
    float* out = (float*)d_out;

    // workspace carve (bf16 elements). Aliases with disjoint lifetimes:
    //   ab     aliases Xq (Xq dead after q-proj gemm)
    //   scores aliases Xk (Xk dead after k-proj gemm)
    us* w = (us*)d_ws;
    us* Xq  = w;                          // 8192*1024
    us* ab  = w;                          // 8192*896 (alias of Xq)
    us* Xk  = Xq  + (size_t)M_ROWS * D_MODEL;
    float* scores = (float*)Xk;           // 5*8192*32 f32 (alias of Xk)
    us* Xv  = Xk  + (size_t)M_ROWS * D_MODEL;
    us* Wqt = Xv  + (size_t)M_ROWS * D_MODEL;           // [320][1024]
    us* Wkt = Wqt + (size_t)SUBHEADS * D_INT * D_MODEL;
    us* Wvt = Wkt + (size_t)SUBHEADS * D_INT * D_MODEL; // [896][1024]
    us* Wct = Wvt + (size_t)HEADS * D_INT * D_MODEL;    // [1024][896]
    us* qbuf = Wct + (size_t)D_MODEL * N_CAT;           // [8192][320]
    us* kbuf = qbuf + (size_t)M_ROWS * NQK;
    us* vbuf = kbuf + (size_t)M_ROWS * NQK;             // [8192][896]

    const int n4 = M_ROWS * D_MODEL / 4;
    cast_bf16<<<dim3(n4 / 256), dim3(256), 0, stream>>>((const float4*)query, Xq, n4);
    cast_bf16<<<dim3(n4 / 256), dim3(256), 0, stream>>>((const float4*)key,   Xk, n4);
    cast_bf16<<<dim3(n4 / 256), dim3(256), 0, stream>>>((const float4*)value, Xv, n4);

    {
        int tq = SUBHEADS * D_MODEL * D_INT;
        tcast<<<dim3((tq + 255) / 256), dim3(256), 0, stream>>>(Wq, Wqt, D_MODEL, D_INT, tq);
        tcast<<<dim3((tq + 255) / 256), dim3(256), 0, stream>>>(Wk, Wkt, D_MODEL, D_INT, tq);
        int tv = HEADS * D_MODEL * D_INT;
        tcast<<<dim3((tv + 255) / 256), dim3(256), 0, stream>>>(Wv, Wvt, D_MODEL, D_INT, tv);
        int tc = N_CAT * D_MODEL;
        tcast<<<dim3((tc + 255) / 256), dim3(256), 0, stream>>>(Wc, Wct, N_CAT, D_MODEL, tc);
    }

    dim3 blk(256);
    // fused projections: q,k -> [8192][320]; v -> [8192][896] (all bf16 out)
    gemm_bf16<<<dim3(M_ROWS / 128, NQK / 64), blk, 0, stream>>>(
        Xq, Wqt, bq, qbuf, D_MODEL, NQK, 1);
    gemm_bf16<<<dim3(M_ROWS / 128, NQK / 64), blk, 0, stream>>>(
        Xk, Wkt, bk, kbuf, D_MODEL, NQK, 1);
    gemm_bf16<<<dim3(M_ROWS / 128, N_CAT / 64), blk, 0, stream>>>(
        Xv, Wvt, bv, vbuf, D_MODEL, N_CAT, 1);

    score_kernel<<<dim3(M_ROWS / 64, SUBHEADS), blk, 0, stream>>>(qbuf, kbuf, scores);
    head_kernel<<<dim3(M_ROWS / 64, HEADS), blk, 0, stream>>>(scores, vbuf, Ws, bs, ab);

    // out gemm: [8192][896] @ [896][1024] -> fp32
    gemm_bf16<<<dim3(M_ROWS / 128, D_MODEL / 64), blk, 0, stream>>>(
        ab, Wct, bc, out, N_CAT, D_MODEL, 0);
}

// Round 5
// 301.520 us; speedup vs baseline: 3.7441x; 1.0615x over previous
//
#include <hip/hip_runtime.h>
#include <math.h>

#define D_MODEL 1024
#define D_INT   64
#define KW      32
#define L_SEQ   4096
#define SUBHEADS 5
#define HEADS   14
#define M_ROWS  8192
#define N_CAT   896
#define NQK     320          // SUBHEADS*64
#define WMAX    312          // 64 + 31*8 (max slab rows, d=8)

typedef unsigned short us;
typedef unsigned int   uu;
typedef __attribute__((ext_vector_type(2))) unsigned int uu2;
typedef __attribute__((ext_vector_type(4))) unsigned int uu4;
typedef __attribute__((ext_vector_type(8))) short bf16x8_t;
typedef __attribute__((ext_vector_type(4))) float f32x4_t;

__device__ __forceinline__ float u2f(uu u) {
    float f; __builtin_memcpy(&f, &u, 4); return f;
}
__device__ __forceinline__ float blo(uu u) { return u2f(u << 16); }
__device__ __forceinline__ float bhi(uu u) { return u2f(u & 0xffff0000u); }
__device__ __forceinline__ us f2b(float f) {
    uu u; __builtin_memcpy(&u, &f, 4);
    u += 0x7fffu + ((u >> 16) & 1u);
    return (us)(u >> 16);
}
__device__ __forceinline__ void load16(void* lds, const void* g) {
    __builtin_amdgcn_global_load_lds(
        (const __attribute__((address_space(1))) unsigned int*)g,
        (__attribute__((address_space(3))) unsigned int*)lds, 16, 0, 0);
}
__device__ __forceinline__ int subhead_of(int h) {
    return (h < 5) ? 0 : (h < 10) ? 1 : (h < 12) ? 2 : (h == 12) ? 3 : 4;
}
__device__ __forceinline__ int dil_of_sub(int s) {
    return (s <= 1) ? 1 : (1 << (s - 1));   // 1,1,2,4,8
}

// ---------------------------------------------------------------------------
// fused fp32 -> bf16 cast for q/k/v (blockIdx.y selects tensor)
// ---------------------------------------------------------------------------
__global__ __launch_bounds__(256)
void cast3_bf16(const float4* __restrict__ s0, const float4* __restrict__ s1,
                const float4* __restrict__ s2, us* __restrict__ d0,
                us* __restrict__ d1, us* __restrict__ d2, int n4)
{
    int i = blockIdx.x * 256 + threadIdx.x;
    if (i >= n4) return;
    const float4* s = (blockIdx.y == 0) ? s0 : (blockIdx.y == 1) ? s1 : s2;
    us* d = (blockIdx.y == 0) ? d0 : (blockIdx.y == 1) ? d1 : d2;
    float4 v = s[i];
    ushort4 o;
    o.x = f2b(v.x); o.y = f2b(v.y); o.z = f2b(v.z); o.w = f2b(v.w);
    ((ushort4*)d)[i] = o;
}

// ---------------------------------------------------------------------------
// LDS-tiled transpose+cast: dst[b][n][k] = src[b][k][n]
// grid (K/32, N/32, batch), block 256 (32x8)
// ---------------------------------------------------------------------------
__global__ __launch_bounds__(256)
void tcast(const float* __restrict__ s, us* __restrict__ d, int K, int N)
{
    __shared__ float t[32][33];
    const int b = blockIdx.z;
    const int k0 = blockIdx.x * 32, n0 = blockIdx.y * 32;
    const int tx = threadIdx.x & 31, ty = threadIdx.x >> 5;
#pragma unroll
    for (int r = 0; r < 32; r += 8)
        t[r + ty][tx] = s[((size_t)b * K + k0 + r + ty) * N + n0 + tx];
    __syncthreads();
#pragma unroll
    for (int r = 0; r < 32; r += 8)
        d[((size_t)b * N + n0 + r + ty) * K + k0 + tx] = f2b(t[tx][r + ty]);
}

// ---------------------------------------------------------------------------
// bf16 MFMA GEMM, 128x64 tile (used for q/k projections, N=320)
// ---------------------------------------------------------------------------
__global__ __launch_bounds__(256)
void gemm_bf16(const us* __restrict__ A, const us* __restrict__ Bt,
               const float* __restrict__ bias, void* __restrict__ Cv,
               int K, int ldC, int outBf16)
{
    __shared__ us As[128 * 64];
    __shared__ us Bs[64 * 64];
    const int row0 = blockIdx.x << 7, col0 = blockIdx.y << 6;
    const int tid = threadIdx.x, w = tid >> 6, lane = tid & 63;
    const int m = lane & 15, quad = lane >> 4;
    const int sr = lane >> 3;
    const int scs = (lane & 7) ^ sr;

    f32x4_t z = {0.f, 0.f, 0.f, 0.f};
    f32x4_t acc[2][4] = {{z, z, z, z}, {z, z, z, z}};

    for (int k0 = 0; k0 < K; k0 += 64) {
#pragma unroll
        for (int p = 0; p < 4; p++) {
            const int r = w * 32 + p * 8 + sr;
            load16(&As[(w * 32 + p * 8) * 64], A + (size_t)(row0 + r) * K + k0 + scs * 8);
        }
#pragma unroll
        for (int p = 0; p < 2; p++) {
            const int r = w * 16 + p * 8 + sr;
            load16(&Bs[(w * 16 + p * 8) * 64], Bt + (size_t)(col0 + r) * K + k0 + scs * 8);
        }
        __syncthreads();
#pragma unroll
        for (int ks = 0; ks < 2; ks++) {
            const int slot = ((ks * 4 + quad) ^ (m & 7)) * 8;
            bf16x8_t a0 = *(const bf16x8_t*)&As[(w * 32 + m) * 64 + slot];
            bf16x8_t a1 = *(const bf16x8_t*)&As[(w * 32 + 16 + m) * 64 + slot];
#pragma unroll
            for (int t = 0; t < 4; t++) {
                bf16x8_t bb = *(const bf16x8_t*)&Bs[(t * 16 + m) * 64 + slot];
                acc[0][t] = __builtin_amdgcn_mfma_f32_16x16x32_bf16(a0, bb, acc[0][t], 0, 0, 0);
                acc[1][t] = __builtin_amdgcn_mfma_f32_16x16x32_bf16(a1, bb, acc[1][t], 0, 0, 0);
            }
        }
        __syncthreads();
    }

#pragma unroll
    for (int tm = 0; tm < 2; tm++) {
        const int rbase = row0 + w * 32 + tm * 16 + quad * 4;
        if (outBf16) {
            us* Cb = (us*)Cv;
#pragma unroll
            for (int t = 0; t < 4; t++) {
                const int col = col0 + t * 16 + m;
                const float bi = bias[col];
#pragma unroll
                for (int r = 0; r < 4; r++)
                    Cb[(size_t)(rbase + r) * ldC + col] = f2b(acc[tm][t][r] + bi);
            }
        } else {
            float* Cb = (float*)Cv;
#pragma unroll
            for (int t = 0; t < 4; t++) {
                const int col = col0 + t * 16 + m;
                const float bi = bias[col];
#pragma unroll
                for (int r = 0; r < 4; r++)
                    Cb[(size_t)(rbase + r) * ldC + col] = acc[tm][t][r] + bi;
            }
        }
    }
}

// ---------------------------------------------------------------------------
// bf16 MFMA GEMM, 128x128 tile (m97 structure): wave = 64x64 quadrant.
// grid (M/128, N/128).
// ---------------------------------------------------------------------------
__global__ __launch_bounds__(256)
void gemm_bf16_128(const us* __restrict__ A, const us* __restrict__ Bt,
                   const float* __restrict__ bias, void* __restrict__ Cv,
                   int K, int ldC, int outBf16)
{
    __shared__ us As[128 * 64];
    __shared__ us Bs[128 * 64];
    const int row0 = blockIdx.x << 7, col0 = blockIdx.y << 7;
    const int tid = threadIdx.x, w = tid >> 6, lane = tid & 63;
    const int m = lane & 15, quad = lane >> 4;
    const int sr = lane >> 3;
    const int scs = (lane & 7) ^ sr;
    const int mrow0 = (w & 1) * 64, ncol0 = (w >> 1) * 64;

    f32x4_t z = {0.f, 0.f, 0.f, 0.f};
    f32x4_t acc[4][4] = {{z,z,z,z},{z,z,z,z},{z,z,z,z},{z,z,z,z}};

    for (int k0 = 0; k0 < K; k0 += 64) {
#pragma unroll
        for (int p = 0; p < 4; p++) {
            const int r = w * 32 + p * 8 + sr;
            load16(&As[(w * 32 + p * 8) * 64], A  + (size_t)(row0 + r) * K + k0 + scs * 8);
            load16(&Bs[(w * 32 + p * 8) * 64], Bt + (size_t)(col0 + r) * K + k0 + scs * 8);
        }
        __syncthreads();
#pragma unroll
        for (int ks = 0; ks < 2; ks++) {
            const int slot = ((ks * 4 + quad) ^ (m & 7)) * 8;
            bf16x8_t a[4], b[4];
#pragma unroll
            for (int t = 0; t < 4; t++) {
                a[t] = *(const bf16x8_t*)&As[(mrow0 + t * 16 + m) * 64 + slot];
                b[t] = *(const bf16x8_t*)&Bs[(ncol0 + t * 16 + m) * 64 + slot];
            }
#pragma unroll
            for (int i = 0; i < 4; i++)
#pragma unroll
                for (int j = 0; j < 4; j++)
                    acc[i][j] = __builtin_amdgcn_mfma_f32_16x16x32_bf16(a[i], b[j], acc[i][j], 0, 0, 0);
        }
        __syncthreads();
    }

#pragma unroll
    for (int i = 0; i < 4; i++) {
        const int rbase = row0 + mrow0 + i * 16 + quad * 4;
        if (outBf16) {
            us* Cb = (us*)Cv;
#pragma unroll
            for (int j = 0; j < 4; j++) {
                const int col = col0 + ncol0 + j * 16 + m;
                const float bi = bias[col];
#pragma unroll
                for (int r = 0; r < 4; r++)
                    Cb[(size_t)(rbase + r) * ldC + col] = f2b(acc[i][j][r] + bi);
            }
        } else {
            float* Cb = (float*)Cv;
#pragma unroll
            for (int j = 0; j < 4; j++) {
                const int col = col0 + ncol0 + j * 16 + m;
                const float bi = bias[col];
#pragma unroll
                for (int r = 0; r < 4; r++)
                    Cb[(size_t)(rbase + r) * ldC + col] = acc[i][j][r] + bi;
            }
        }
    }
}

// ---------------------------------------------------------------------------
// Score kernel: block = (64 positions, subhead). Lane = window index j,
// half = position parity. K/Q slabs in LDS, float4 (b128) dot-product reads.
// kslab stride 36 dwords (16B-aligned rows, bank-uniform for d<=4).
// scores: [S][8192][32] f32.  grid (128, 5).
// ---------------------------------------------------------------------------
__global__ __launch_bounds__(256)
void score_kernel(const us* __restrict__ qb, const us* __restrict__ kb,
                  float* __restrict__ scores)
{
    __shared__ uu kslab[WMAX * 36];
    __shared__ uu qslab[64 * 32];

    const int tid  = threadIdx.x;
    const int wave = tid >> 6;
    const int lane = tid & 63;
    const int j    = lane & 31;
    const int half = lane >> 5;
    const int s    = blockIdx.y;
    const int d    = dil_of_sub(s);
    const int ml0  = blockIdx.x * 64;
    const int l0   = ml0 & 4095;
    const int bm   = ml0 - l0;
    const int W    = 64 + 31 * d;

    const uu* kg = (const uu*)kb;
    const uu* qg = (const uu*)qb;

    for (int idx = tid; idx < W * 32; idx += 256) {
        int r = idx >> 5, c = idx & 31;
        int src = l0 - 16 * d + r;
        src = src < 0 ? 0 : (src > 4095 ? 4095 : src);
        kslab[r * 36 + c] = kg[(size_t)(bm + src) * 160 + s * 32 + c];
    }
    for (int idx = tid; idx < 64 * 32; idx += 256) {
        int r = idx >> 5, c = idx & 31;
        qslab[r * 32 + c] = qg[(size_t)(ml0 + r) * 160 + s * 32 + c];
    }
    __syncthreads();

#pragma unroll
    for (int i = 0; i < 8; i++) {
        const int p = wave * 16 + i * 2 + half;
        const uu4* k4 = (const uu4*)&kslab[(p + j * d) * 36];
        const uu4* q4 = (const uu4*)&qslab[p * 32];
        float acc = 0.f;
#pragma unroll
        for (int q = 0; q < 8; q++) {
            uu4 kd = k4[q];
            uu4 qd = q4[q];
#pragma unroll
            for (int u = 0; u < 4; u++) {
                acc = fmaf(blo(kd[u]), blo(qd[u]), acc);
                acc = fmaf(bhi(kd[u]), bhi(qd[u]), acc);
            }
        }
        scores[((size_t)s * M_ROWS + ml0 + p) * 32 + j] = acc * 0.125f;
    }
}

// ---------------------------------------------------------------------------
// Head kernel: block = (64 positions, head).
// Phase 0: stage V slab (stride 34, pre-clamped) + score tile into LDS.
// Phase 1: resample (float4 LDS reads, Ws column in regs) + softmax
//          (lane = m column, 2 positions/wave-iter); attn -> LDS.
// Phase 2: PV with remapped lanes (pp = lane>>4 position-of-quad,
//          cq = lane&15 channel-quad); attn float4, V b64 reads.
// grid (128, 14).
// ---------------------------------------------------------------------------
__global__ __launch_bounds__(256)
void head_kernel(const float* __restrict__ scores, const us* __restrict__ vb,
                 const float* __restrict__ Ws, const float* __restrict__ bs,
                 us* __restrict__ ab)
{
    __shared__ uu    vslab[WMAX * 34];   // 42.4 KB
    __shared__ float scb[64 * 32];       // 8 KB
    __shared__ float atb[64 * 32];       // 8 KB

    const int tid  = threadIdx.x;
    const int wave = tid >> 6;
    const int lane = tid & 63;
    const int j    = lane & 31;
    const int half = lane >> 5;
    const int h    = blockIdx.y;
    const int s    = subhead_of(h);
    const int d    = dil_of_sub(s);
    const int ml0  = blockIdx.x * 64;
    const int l0   = ml0 & 4095;
    const int bm   = ml0 - l0;
    const int W    = 64 + 31 * d;

    const uu* vg = (const uu*)vb;
    for (int idx = tid; idx < W * 32; idx += 256) {
        int r = idx >> 5, c = idx & 31;
        int src = l0 - 16 * d + r;
        src = src < 0 ? 0 : (src > 4095 ? 4095 : src);
        vslab[r * 34 + c] = vg[(size_t)(bm + src) * 448 + h * 32 + c];
    }
#pragma unroll
    for (int t = 0; t < 8; t++) {
        int idx = t * 256 + tid;
        scb[idx] = scores[((size_t)s * M_ROWS + ml0) * 32 + idx];
    }

    float wsr[32];
#pragma unroll
    for (int k = 0; k < 32; k++) wsr[k] = Ws[(size_t)h * 1024 + k * 32 + j];
    const float bsv = bs[h * 32 + j];
    __syncthreads();

    // ---- phase 1: resample + softmax (2 positions per iteration) ----
#pragma unroll
    for (int i = 0; i < 8; i++) {
        const int p = wave * 16 + i * 2 + half;
        const float4* s4 = (const float4*)&scb[p * 32];
        float acc = bsv;
#pragma unroll
        for (int q = 0; q < 8; q++) {
            float4 v = s4[q];
            acc = fmaf(v.x, wsr[q * 4 + 0], acc);
            acc = fmaf(v.y, wsr[q * 4 + 1], acc);
            acc = fmaf(v.z, wsr[q * 4 + 2], acc);
            acc = fmaf(v.w, wsr[q * 4 + 3], acc);
        }
        float mx = acc;
#pragma unroll
        for (int off = 16; off > 0; off >>= 1) mx = fmaxf(mx, __shfl_xor(mx, off, 64));
        float ex = __expf(acc - mx);
        float sum = ex;
#pragma unroll
        for (int off = 16; off > 0; off >>= 1) sum += __shfl_xor(sum, off, 64);
        atb[p * 32 + j] = ex / sum;
    }
    // no barrier: phase 2 reads only this wave's own atb rows (wave-coherent)

    // ---- phase 2: PV, remapped lanes ----
    const int pp = lane >> 4;      // position within quad-group
    const int cq = lane & 15;      // channel quad (4 channels = 2 dwords)
#pragma unroll
    for (int g = 0; g < 4; g++) {
        const int p  = wave * 16 + g * 4 + pp;
        const int ml = ml0 + p;
        const float4* a4 = (const float4*)&atb[p * 32];
        float o0 = 0.f, o1 = 0.f, o2 = 0.f, o3 = 0.f;
#pragma unroll
        for (int q = 0; q < 8; q++) {
            float4 a = a4[q];
#pragma unroll
            for (int u = 0; u < 4; u++) {
                const int mm = q * 4 + u;
                uu2 vd = *(const uu2*)&vslab[(p + mm * d) * 34 + cq * 2];
                const float av = (u == 0) ? a.x : (u == 1) ? a.y : (u == 2) ? a.z : a.w;
                o0 = fmaf(blo(vd.x), av, o0);
                o1 = fmaf(bhi(vd.x), av, o1);
                o2 = fmaf(blo(vd.y), av, o2);
                o3 = fmaf(bhi(vd.y), av, o3);
            }
        }
        uu2 od;
        od.x = (uu)f2b(o0) | ((uu)f2b(o1) << 16);
        od.y = (uu)f2b(o2) | ((uu)f2b(o3) << 16);
        *(uu2*)&((uu*)ab)[(size_t)ml * 448 + h * 32 + cq * 2] = od;
    }
}

// ---------------------------------------------------------------------------
extern "C" void kernel_launch(void* const* d_in, const int* in_sizes, int n_in,
                              void* d_out, int out_size, void* d_ws, size_t ws_size,
                              hipStream_t stream)
{
    const float* query = (const float*)d_in[0];
    const float* key   = (const float*)d_in[1];
    const float* value = (const float*)d_in[2];
    const float* Wq    = (const float*)d_in[3];
    const float* bq    = (const float*)d_in[4];
    const float* Wk    = (const float*)d_in[5];
    const float* bk    = (const float*)d_in[6];
    const float* Wv    = (const float*)d_in[7];
    const float* bv    = (const float*)d_in[8];
    const float* Ws    = (const float*)d_in[9];
    const float* bs    = (const float*)d_in[10];
    const float* Wc    = (const float*)d_in[11];
    const float* bc    = (const float*)d_in[12];
    float* out = (float*)d_out;

    // workspace carve (bf16 elements). Aliases with disjoint lifetimes:
    //   ab aliases Xq; scores aliases Xk.
    us* w = (us*)d_ws;
    us* Xq  = w;                          // 8192*1024
    us* ab  = w;                          // 8192*896 (alias of Xq)
    us* Xk  = Xq  + (size_t)M_ROWS * D_MODEL;
    float* scores = (float*)Xk;           // 5*8192*32 f32 (alias of Xk)
    us* Xv  = Xk  + (size_t)M_ROWS * D_MODEL;
    us* Wqt = Xv  + (size_t)M_ROWS * D_MODEL;           // [320][1024]
    us* Wkt = Wqt + (size_t)SUBHEADS * D_INT * D_MODEL;
    us* Wvt = Wkt + (size_t)SUBHEADS * D_INT * D_MODEL; // [896][1024]
    us* Wct = Wvt + (size_t)HEADS * D_INT * D_MODEL;    // [1024][896]
    us* qbuf = Wct + (size_t)D_MODEL * N_CAT;           // [8192][320]
    us* kbuf = qbuf + (size_t)M_ROWS * NQK;
    us* vbuf = kbuf + (size_t)M_ROWS * NQK;             // [8192][896]

    const int n4 = M_ROWS * D_MODEL / 4;
    cast3_bf16<<<dim3(n4 / 256, 3), dim3(256), 0, stream>>>(
        (const float4*)query, (const float4*)key, (const float4*)value,
        Xq, Xk, Xv, n4);

    // weight transposes (LDS-tiled, coalesced both sides)
    tcast<<<dim3(D_MODEL / 32, D_INT / 32, SUBHEADS), dim3(256), 0, stream>>>(Wq, Wqt, D_MODEL, D_INT);
    tcast<<<dim3(D_MODEL / 32, D_INT / 32, SUBHEADS), dim3(256), 0, stream>>>(Wk, Wkt, D_MODEL, D_INT);
    tcast<<<dim3(D_MODEL / 32, D_INT / 32, HEADS),    dim3(256), 0, stream>>>(Wv, Wvt, D_MODEL, D_INT);
    tcast<<<dim3(N_CAT / 32, D_MODEL / 32, 1),        dim3(256), 0, stream>>>(Wc, Wct, N_CAT, D_MODEL);

    dim3 blk(256);
    // q,k projections: [8192][320] bf16 (128x64 tile; N=320)
    gemm_bf16<<<dim3(M_ROWS / 128, NQK / 64), blk, 0, stream>>>(
        Xq, Wqt, bq, qbuf, D_MODEL, NQK, 1);
    gemm_bf16<<<dim3(M_ROWS / 128, NQK / 64), blk, 0, stream>>>(
        Xk, Wkt, bk, kbuf, D_MODEL, NQK, 1);
    // v projection: [8192][896] bf16 (128x128 tile)
    gemm_bf16_128<<<dim3(M_ROWS / 128, N_CAT / 128), blk, 0, stream>>>(
        Xv, Wvt, bv, vbuf, D_MODEL, N_CAT, 1);

    score_kernel<<<dim3(M_ROWS / 64, SUBHEADS), blk, 0, stream>>>(qbuf, kbuf, scores);
    head_kernel<<<dim3(M_ROWS / 64, HEADS), blk, 0, stream>>>(scores, vbuf, Ws, bs, ab);

    // out gemm: [8192][896] @ [896][1024] -> fp32 (128x128 tile)
    gemm_bf16_128<<<dim3(M_ROWS / 128, D_MODEL / 128), blk, 0, stream>>>(
        ab, Wct, bc, out, N_CAT, D_MODEL, 0);
}

// Round 6
// 284.871 us; speedup vs baseline: 3.9629x; 1.0584x over previous
//
#include <hip/hip_runtime.h>
#include <math.h>

#define D_MODEL 1024
#define D_INT   64
#define KW      32
#define L_SEQ   4096
#define SUBHEADS 5
#define HEADS   14
#define M_ROWS  8192
#define N_CAT   896
#define NQK     320          // SUBHEADS*64

typedef unsigned short us;
typedef unsigned int   uu;
typedef __attribute__((ext_vector_type(4))) unsigned int uu4;
typedef __attribute__((ext_vector_type(8))) short bf16x8_t;
typedef __attribute__((ext_vector_type(4))) float f32x4_t;

__device__ __forceinline__ float u2f(uu u) {
    float f; __builtin_memcpy(&f, &u, 4); return f;
}
__device__ __forceinline__ float blo(uu u) { return u2f(u << 16); }
__device__ __forceinline__ float bhi(uu u) { return u2f(u & 0xffff0000u); }
__device__ __forceinline__ us f2b(float f) {
    uu u; __builtin_memcpy(&u, &f, 4);
    u += 0x7fffu + ((u >> 16) & 1u);
    return (us)(u >> 16);
}
__device__ __forceinline__ uu pack2(float a, float b) {
    return (uu)f2b(a) | ((uu)f2b(b) << 16);
}
__device__ __forceinline__ void load16(void* lds, const void* g) {
    __builtin_amdgcn_global_load_lds(
        (const __attribute__((address_space(1))) unsigned int*)g,
        (__attribute__((address_space(3))) unsigned int*)lds, 16, 0, 0);
}
__device__ __forceinline__ int subhead_of(int h) {
    return (h < 5) ? 0 : (h < 10) ? 1 : (h < 12) ? 2 : (h == 12) ? 3 : 4;
}
__device__ __forceinline__ int dil_of_sub(int s) {
    return (s <= 1) ? 1 : (1 << (s - 1));   // 1,1,2,4,8
}

// ---------------------------------------------------------------------------
// Prep mega-kernel: 3 fp32->bf16 casts (q,k,v) + 4 transpose-casts (Wq,Wk,Wv,Wc)
// grid: 24576 cast blocks + 320+320+896+896 tcast blocks = 27008
// ---------------------------------------------------------------------------
#define CAST_BLK 24576
__global__ __launch_bounds__(256)
void prep_kernel(const float4* __restrict__ q, const float4* __restrict__ k,
                 const float4* __restrict__ v,
                 const float* __restrict__ Wq, const float* __restrict__ Wk,
                 const float* __restrict__ Wv, const float* __restrict__ Wc,
                 us* __restrict__ Xq, us* __restrict__ Xk, us* __restrict__ Xv,
                 us* __restrict__ Wqt, us* __restrict__ Wkt,
                 us* __restrict__ Wvt, us* __restrict__ Wct)
{
    __shared__ float t[32][33];
    const int b = blockIdx.x, tid = threadIdx.x;

    if (b < CAST_BLK) {
        const int which = b >> 13;
        const int i = ((b & 8191) << 8) + tid;
        const float4* s = (which == 0) ? q : (which == 1) ? k : v;
        us* d = (which == 0) ? Xq : (which == 1) ? Xk : Xv;
        float4 x = s[i];
        ushort4 o;
        o.x = f2b(x.x); o.y = f2b(x.y); o.z = f2b(x.z); o.w = f2b(x.w);
        ((ushort4*)d)[i] = o;
        return;
    }

    int g = b - CAST_BLK;
    const float* S; us* D; int K, N;
    if (g < 640) {
        if (g < 320) { S = Wq; D = Wqt; } else { S = Wk; D = Wkt; g -= 320; }
        K = 1024; N = 64;
    } else if (g < 1536) {
        g -= 640; S = Wv; D = Wvt; K = 1024; N = 64;
    } else {
        g -= 1536; S = Wc; D = Wct; K = 896; N = 1024;
    }
    const int nkx = K >> 5;
    const int kx = g % nkx;
    const int rest = g / nkx;
    const int ny = rest % (N >> 5);
    const int z  = rest / (N >> 5);
    const int k0 = kx * 32, n0 = ny * 32;
    S += (size_t)z * K * N;
    D += (size_t)z * K * N;
    const int tx = tid & 31, ty = tid >> 5;
#pragma unroll
    for (int r = 0; r < 32; r += 8)
        t[r + ty][tx] = S[(size_t)(k0 + r + ty) * N + n0 + tx];
    __syncthreads();
#pragma unroll
    for (int r = 0; r < 32; r += 8)
        D[(size_t)(n0 + r + ty) * K + k0 + tx] = f2b(t[tx][r + ty]);
}

// ---------------------------------------------------------------------------
// shared 128x64-tile GEMM core (BK=64, XOR-swizzled LDS, global_load_lds 16B)
// ---------------------------------------------------------------------------
__device__ __forceinline__
void gemm64_core(const us* __restrict__ A, const us* __restrict__ Bt,
                 const float* __restrict__ bias, us* __restrict__ C,
                 int K, int ldC, us* As, us* Bs)
{
    const int row0 = blockIdx.x << 7, col0 = blockIdx.y << 6;
    const int tid = threadIdx.x, w = tid >> 6, lane = tid & 63;
    const int m = lane & 15, quad = lane >> 4;
    const int sr = lane >> 3;
    const int scs = (lane & 7) ^ sr;

    f32x4_t z4 = {0.f, 0.f, 0.f, 0.f};
    f32x4_t acc[2][4] = {{z4, z4, z4, z4}, {z4, z4, z4, z4}};

    for (int k0 = 0; k0 < K; k0 += 64) {
#pragma unroll
        for (int p = 0; p < 4; p++) {
            const int r = w * 32 + p * 8 + sr;
            load16(&As[(w * 32 + p * 8) * 64], A + (size_t)(row0 + r) * K + k0 + scs * 8);
        }
#pragma unroll
        for (int p = 0; p < 2; p++) {
            const int r = w * 16 + p * 8 + sr;
            load16(&Bs[(w * 16 + p * 8) * 64], Bt + (size_t)(col0 + r) * K + k0 + scs * 8);
        }
        __syncthreads();
#pragma unroll
        for (int ks = 0; ks < 2; ks++) {
            const int slot = ((ks * 4 + quad) ^ (m & 7)) * 8;
            bf16x8_t a0 = *(const bf16x8_t*)&As[(w * 32 + m) * 64 + slot];
            bf16x8_t a1 = *(const bf16x8_t*)&As[(w * 32 + 16 + m) * 64 + slot];
#pragma unroll
            for (int t = 0; t < 4; t++) {
                bf16x8_t bb = *(const bf16x8_t*)&Bs[(t * 16 + m) * 64 + slot];
                acc[0][t] = __builtin_amdgcn_mfma_f32_16x16x32_bf16(a0, bb, acc[0][t], 0, 0, 0);
                acc[1][t] = __builtin_amdgcn_mfma_f32_16x16x32_bf16(a1, bb, acc[1][t], 0, 0, 0);
            }
        }
        __syncthreads();
    }

#pragma unroll
    for (int tm = 0; tm < 2; tm++) {
        const int rbase = row0 + w * 32 + tm * 16 + quad * 4;
#pragma unroll
        for (int t = 0; t < 4; t++) {
            const int col = col0 + t * 16 + m;
            const float bi = bias[col];
#pragma unroll
            for (int r = 0; r < 4; r++)
                C[(size_t)(rbase + r) * ldC + col] = f2b(acc[tm][t][r] + bi);
        }
    }
}

// fused q/k projection: grid (64, 5, 2)
__global__ __launch_bounds__(256)
void gemm_qk(const us* __restrict__ Xq, const us* __restrict__ Xk,
             const us* __restrict__ Wqt, const us* __restrict__ Wkt,
             const float* __restrict__ bq, const float* __restrict__ bk,
             us* __restrict__ qbuf, us* __restrict__ kbuf)
{
    __shared__ us As[128 * 64];
    __shared__ us Bs[64 * 64];
    const int z = blockIdx.z;
    gemm64_core(z ? Xk : Xq, z ? Wkt : Wqt, z ? bk : bq, z ? kbuf : qbuf,
                D_MODEL, NQK, As, Bs);
}

// ---------------------------------------------------------------------------
// bf16 MFMA GEMM, 128x128 tile (m97 structure): wave = 64x64 quadrant.
// ---------------------------------------------------------------------------
__global__ __launch_bounds__(256)
void gemm_bf16_128(const us* __restrict__ A, const us* __restrict__ Bt,
                   const float* __restrict__ bias, void* __restrict__ Cv,
                   int K, int ldC, int outBf16)
{
    __shared__ us As[128 * 64];
    __shared__ us Bs[128 * 64];
    const int row0 = blockIdx.x << 7, col0 = blockIdx.y << 7;
    const int tid = threadIdx.x, w = tid >> 6, lane = tid & 63;
    const int m = lane & 15, quad = lane >> 4;
    const int sr = lane >> 3;
    const int scs = (lane & 7) ^ sr;
    const int mrow0 = (w & 1) * 64, ncol0 = (w >> 1) * 64;

    f32x4_t z = {0.f, 0.f, 0.f, 0.f};
    f32x4_t acc[4][4] = {{z,z,z,z},{z,z,z,z},{z,z,z,z},{z,z,z,z}};

    for (int k0 = 0; k0 < K; k0 += 64) {
#pragma unroll
        for (int p = 0; p < 4; p++) {
            const int r = w * 32 + p * 8 + sr;
            load16(&As[(w * 32 + p * 8) * 64], A  + (size_t)(row0 + r) * K + k0 + scs * 8);
            load16(&Bs[(w * 32 + p * 8) * 64], Bt + (size_t)(col0 + r) * K + k0 + scs * 8);
        }
        __syncthreads();
#pragma unroll
        for (int ks = 0; ks < 2; ks++) {
            const int slot = ((ks * 4 + quad) ^ (m & 7)) * 8;
            bf16x8_t a[4], b[4];
#pragma unroll
            for (int t = 0; t < 4; t++) {
                a[t] = *(const bf16x8_t*)&As[(mrow0 + t * 16 + m) * 64 + slot];
                b[t] = *(const bf16x8_t*)&Bs[(ncol0 + t * 16 + m) * 64 + slot];
            }
#pragma unroll
            for (int i = 0; i < 4; i++)
#pragma unroll
                for (int j = 0; j < 4; j++)
                    acc[i][j] = __builtin_amdgcn_mfma_f32_16x16x32_bf16(a[i], b[j], acc[i][j], 0, 0, 0);
        }
        __syncthreads();
    }

#pragma unroll
    for (int i = 0; i < 4; i++) {
        const int rbase = row0 + mrow0 + i * 16 + quad * 4;
        if (outBf16) {
            us* Cb = (us*)Cv;
#pragma unroll
            for (int j = 0; j < 4; j++) {
                const int col = col0 + ncol0 + j * 16 + m;
                const float bi = bias[col];
#pragma unroll
                for (int r = 0; r < 4; r++)
                    Cb[(size_t)(rbase + r) * ldC + col] = f2b(acc[i][j][r] + bi);
            }
        } else {
            float* Cb = (float*)Cv;
#pragma unroll
            for (int j = 0; j < 4; j++) {
                const int col = col0 + ncol0 + j * 16 + m;
                const float bi = bias[col];
#pragma unroll
                for (int r = 0; r < 4; r++)
                    Cb[(size_t)(rbase + r) * ldC + col] = acc[i][j][r] + bi;
            }
        }
    }
}

// ---------------------------------------------------------------------------
// Score kernel (templated slab rows; split by dilation for occupancy).
// Lane = window index j, half = position parity. b128 LDS dot-product reads.
// grid (128, nsub), sbase selects subhead range.
// ---------------------------------------------------------------------------
template<int ROWS>
__global__ __launch_bounds__(256)
void score_kernel(const us* __restrict__ qb, const us* __restrict__ kb,
                  float* __restrict__ scores, int sbase)
{
    __shared__ uu kslab[ROWS * 36];
    __shared__ uu qslab[64 * 32];

    const int tid  = threadIdx.x;
    const int wave = tid >> 6;
    const int lane = tid & 63;
    const int j    = lane & 31;
    const int half = lane >> 5;
    const int s    = sbase + blockIdx.y;
    const int d    = dil_of_sub(s);
    const int ml0  = blockIdx.x * 64;
    const int l0   = ml0 & 4095;
    const int bm   = ml0 - l0;
    const int W    = 64 + 31 * d;

    const uu* kg = (const uu*)kb;
    const uu* qg = (const uu*)qb;

    for (int idx = tid; idx < W * 32; idx += 256) {
        int r = idx >> 5, c = idx & 31;
        int src = l0 - 16 * d + r;
        src = src < 0 ? 0 : (src > 4095 ? 4095 : src);
        kslab[r * 36 + c] = kg[(size_t)(bm + src) * 160 + s * 32 + c];
    }
    for (int idx = tid; idx < 64 * 32; idx += 256) {
        int r = idx >> 5, c = idx & 31;
        qslab[r * 32 + c] = qg[(size_t)(ml0 + r) * 160 + s * 32 + c];
    }
    __syncthreads();

#pragma unroll
    for (int i = 0; i < 8; i++) {
        const int p = wave * 16 + i * 2 + half;
        const uu4* k4 = (const uu4*)&kslab[(p + j * d) * 36];
        const uu4* q4 = (const uu4*)&qslab[p * 32];
        float acc = 0.f;
#pragma unroll
        for (int q = 0; q < 8; q++) {
            uu4 kd = k4[q];
            uu4 qd = q4[q];
            acc = fmaf(blo(kd.x), blo(qd.x), acc); acc = fmaf(bhi(kd.x), bhi(qd.x), acc);
            acc = fmaf(blo(kd.y), blo(qd.y), acc); acc = fmaf(bhi(kd.y), bhi(qd.y), acc);
            acc = fmaf(blo(kd.z), blo(qd.z), acc); acc = fmaf(bhi(kd.z), bhi(qd.z), acc);
            acc = fmaf(blo(kd.w), blo(qd.w), acc); acc = fmaf(bhi(kd.w), bhi(qd.w), acc);
        }
        scores[((size_t)s * M_ROWS + ml0 + p) * 32 + j] = acc * 0.125f;
    }
}

// ---------------------------------------------------------------------------
// Head kernel (templated slab rows; split by dilation).
// vslab stride 36 (16B-aligned, <=2-way banks). sab: scores overlaid by attn
// (rows are wave-private). Phase 1: resample (b128 broadcast) + softmax.
// Phase 2: PV with lane=(position-octet o, channel-chunk c): one b128 per
// (mm,pass) serves 8 positions; attn broadcast banks (4p+mm) distinct per o.
// grid (128, nheads), hbase selects head range.
// ---------------------------------------------------------------------------
template<int ROWS>
__global__ __launch_bounds__(256)
void head_kernel(const float* __restrict__ scores, const us* __restrict__ vb,
                 const float* __restrict__ Ws, const float* __restrict__ bs,
                 us* __restrict__ ab, int hbase)
{
    __shared__ uu    vslab[ROWS * 36];
    __shared__ float sab[64 * 36];

    const int tid  = threadIdx.x;
    const int wave = tid >> 6;
    const int lane = tid & 63;
    const int j    = lane & 31;
    const int half = lane >> 5;
    const int h    = hbase + blockIdx.y;
    const int s    = subhead_of(h);
    const int d    = dil_of_sub(s);
    const int ml0  = blockIdx.x * 64;
    const int l0   = ml0 & 4095;
    const int bm   = ml0 - l0;
    const int W    = 64 + 31 * d;

    const uu* vg = (const uu*)vb;
    for (int idx = tid; idx < W * 32; idx += 256) {
        int r = idx >> 5, c = idx & 31;
        int src = l0 - 16 * d + r;
        src = src < 0 ? 0 : (src > 4095 ? 4095 : src);
        vslab[r * 36 + c] = vg[(size_t)(bm + src) * 448 + h * 32 + c];
    }
    {
        const float4* g4 = (const float4*)(scores + ((size_t)s * M_ROWS + ml0) * 32);
#pragma unroll
        for (int t = 0; t < 2; t++) {
            int i4 = t * 256 + tid;
            int r = i4 >> 3, c4 = i4 & 7;
            *(float4*)&sab[r * 36 + c4 * 4] = g4[i4];
        }
    }
    float wsr[32];
#pragma unroll
    for (int k = 0; k < 32; k++) wsr[k] = Ws[(size_t)h * 1024 + k * 32 + j];
    const float bsv = bs[h * 32 + j];
    __syncthreads();

    // ---- phase 1: resample + softmax; attn overwrites score row in sab ----
#pragma unroll
    for (int i = 0; i < 8; i++) {
        const int p = wave * 16 + i * 2 + half;
        const float4* s4 = (const float4*)&sab[p * 36];
        float acc = bsv;
#pragma unroll
        for (int q = 0; q < 8; q++) {
            float4 v = s4[q];
            acc = fmaf(v.x, wsr[q * 4 + 0], acc);
            acc = fmaf(v.y, wsr[q * 4 + 1], acc);
            acc = fmaf(v.z, wsr[q * 4 + 2], acc);
            acc = fmaf(v.w, wsr[q * 4 + 3], acc);
        }
        float mx = acc;
#pragma unroll
        for (int off = 16; off > 0; off >>= 1) mx = fmaxf(mx, __shfl_xor(mx, off, 64));
        float ex = __expf(acc - mx);
        float sum = ex;
#pragma unroll
        for (int off = 16; off > 0; off >>= 1) sum += __shfl_xor(sum, off, 64);
        sab[p * 36 + j] = ex / sum;
    }

    // ---- phase 2: PV, 8 positions per pass ----
    const int o = lane >> 3;     // position octet
    const int c = lane & 7;      // channel chunk (4 dwords = 8 channels)
#pragma unroll
    for (int pass = 0; pass < 2; pass++) {
        const int p  = wave * 16 + pass * 8 + o;
        const int ml = ml0 + p;
        float a0 = 0.f, a1 = 0.f, a2 = 0.f, a3 = 0.f;
        float a4 = 0.f, a5 = 0.f, a6 = 0.f, a7 = 0.f;
#pragma unroll
        for (int mm = 0; mm < 32; mm++) {
            const float at = sab[p * 36 + mm];
            uu4 vd = *(const uu4*)&vslab[(p + mm * d) * 36 + c * 4];
            a0 = fmaf(blo(vd.x), at, a0); a1 = fmaf(bhi(vd.x), at, a1);
            a2 = fmaf(blo(vd.y), at, a2); a3 = fmaf(bhi(vd.y), at, a3);
            a4 = fmaf(blo(vd.z), at, a4); a5 = fmaf(bhi(vd.z), at, a5);
            a6 = fmaf(blo(vd.w), at, a6); a7 = fmaf(bhi(vd.w), at, a7);
        }
        uu4 od;
        od.x = pack2(a0, a1); od.y = pack2(a2, a3);
        od.z = pack2(a4, a5); od.w = pack2(a6, a7);
        *(uu4*)&((uu*)ab)[(size_t)ml * 448 + h * 32 + c * 4] = od;
    }
}

// ---------------------------------------------------------------------------
extern "C" void kernel_launch(void* const* d_in, const int* in_sizes, int n_in,
                              void* d_out, int out_size, void* d_ws, size_t ws_size,
                              hipStream_t stream)
{
    const float* query = (const float*)d_in[0];
    const float* key   = (const float*)d_in[1];
    const float* value = (const float*)d_in[2];
    const float* Wq    = (const float*)d_in[3];
    const float* bq    = (const float*)d_in[4];
    const float* Wk    = (const float*)d_in[5];
    const float* bk    = (const float*)d_in[6];
    const float* Wv    = (const float*)d_in[7];
    const float* bv    = (const float*)d_in[8];
    const float* Ws    = (const float*)d_in[9];
    const float* bs    = (const float*)d_in[10];
    const float* Wc    = (const float*)d_in[11];
    const float* bc    = (const float*)d_in[12];
    float* out = (float*)d_out;

    // workspace carve (bf16 elements). Aliases with disjoint lifetimes:
    //   ab aliases Xq (Xq dead after q gemm); scores alias Xk (dead after k gemm)
    us* w = (us*)d_ws;
    us* Xq  = w;                          // 8192*1024
    us* ab  = w;                          // 8192*896 (alias of Xq)
    us* Xk  = Xq  + (size_t)M_ROWS * D_MODEL;
    float* scores = (float*)Xk;           // 5*8192*32 f32 (alias of Xk)
    us* Xv  = Xk  + (size_t)M_ROWS * D_MODEL;
    us* Wqt = Xv  + (size_t)M_ROWS * D_MODEL;           // [320][1024]
    us* Wkt = Wqt + (size_t)SUBHEADS * D_INT * D_MODEL;
    us* Wvt = Wkt + (size_t)SUBHEADS * D_INT * D_MODEL; // [896][1024]
    us* Wct = Wvt + (size_t)HEADS * D_INT * D_MODEL;    // [1024][896]
    us* qbuf = Wct + (size_t)D_MODEL * N_CAT;           // [8192][320]
    us* kbuf = qbuf + (size_t)M_ROWS * NQK;
    us* vbuf = kbuf + (size_t)M_ROWS * NQK;             // [8192][896]

    dim3 blk(256);

    // prep: casts + weight transposes in one launch
    prep_kernel<<<dim3(CAST_BLK + 2432), blk, 0, stream>>>(
        (const float4*)query, (const float4*)key, (const float4*)value,
        Wq, Wk, Wv, Wc, Xq, Xk, Xv, Wqt, Wkt, Wvt, Wct);

    // q+k projections fused: [8192][320] bf16
    gemm_qk<<<dim3(M_ROWS / 128, NQK / 64, 2), blk, 0, stream>>>(
        Xq, Xk, Wqt, Wkt, bq, bk, qbuf, kbuf);

    // v projection: [8192][896] bf16 (128x128 tile)
    gemm_bf16_128<<<dim3(M_ROWS / 128, N_CAT / 128), blk, 0, stream>>>(
        Xv, Wvt, bv, vbuf, D_MODEL, N_CAT, 1);

    // scores, split by dilation (subheads 0-2: W<=126; 3-4: W<=312)
    score_kernel<126><<<dim3(M_ROWS / 64, 3), blk, 0, stream>>>(qbuf, kbuf, scores, 0);
    score_kernel<312><<<dim3(M_ROWS / 64, 2), blk, 0, stream>>>(qbuf, kbuf, scores, 3);

    // heads, split by dilation (heads 0-11: d<=2, W<=126; 12-13: W<=312)
    head_kernel<312><<<dim3(M_ROWS / 64, 2),  blk, 0, stream>>>(scores, vbuf, Ws, bs, ab, 12);
    head_kernel<126><<<dim3(M_ROWS / 64, 12), blk, 0, stream>>>(scores, vbuf, Ws, bs, ab, 0);

    // out gemm: [8192][896] @ [896][1024] -> fp32 (128x128 tile)
    gemm_bf16_128<<<dim3(M_ROWS / 128, D_MODEL / 128), blk, 0, stream>>>(
        ab, Wct, bc, out, N_CAT, D_MODEL, 0);
}